// Round 17
// baseline (167.680 us; speedup 1.0000x reference)
//
#include <hip/hip_runtime.h>
#include <hip/hip_bf16.h>
#include <math.h>

#define BB 4
#define SS 2048
#define HH 8
#define DD 64
#define EPSV 1e-5f

typedef __attribute__((ext_vector_type(8))) short short8;
typedef __attribute__((ext_vector_type(4))) float f32x4;
typedef __attribute__((ext_vector_type(4))) unsigned int uint4v;
typedef unsigned short ushort_t;
#define MFMA16 __builtin_amdgcn_mfma_f32_16x16x32_bf16

__device__ inline unsigned short f2bf(float f) {
    unsigned u = __builtin_bit_cast(unsigned, f);
    unsigned r = (u + 0x7fffu + ((u >> 16) & 1u)) >> 16;
    return (unsigned short)r;
}
__device__ inline float bf2f(unsigned short h) {
    unsigned u = ((unsigned)h) << 16;
    return __builtin_bit_cast(float, u);
}
__device__ inline unsigned pkbf(float a, float b) {
    __hip_bfloat162 h2 = __float22bfloat162_rn(make_float2(a, b));
    unsigned u;
    __builtin_memcpy(&u, &h2, 4);
    return u;
}
// gelu exact via A&S 7.1.26 erf (|err| <= 1.5e-7): rcp + 5 FMA + exp2.
__device__ inline float gelu_f(float v) {
    float a = v * 0.70710678118654752f;
    float z = fabsf(a);
    float t = __builtin_amdgcn_rcpf(fmaf(0.3275911f, z, 1.0f));
    float p = t * fmaf(t, fmaf(t, fmaf(t, fmaf(t, 1.061405429f, -1.453152027f),
                                       1.421413741f), -0.284496736f), 0.254829592f);
    float e = __builtin_amdgcn_exp2f(-z * z * 1.4426950408889634f);
    float erfz = fmaf(-p, e, 1.0f);
    float se = (a < 0.0f) ? -erfz : erfz;
    return 0.5f * v * (1.0f + se);
}

// ---------------------------------------------------------------------------
// K1: LN1 + QKV projection via bf16 MFMA, split-precision for Q and K.
// B-frags built directly from raw Wp. Grid 1024, 64 rows/block, 4 waves.
// Pad 40960 B = 4 blocks/CU (budget 128 >= demand ~125). EXACT R15 kernel.
// ---------------------------------------------------------------------------
__global__ __launch_bounds__(256, 2) void k1_ln_qkv(
    const float* __restrict__ x, const float* __restrict__ g1, const float* __restrict__ b1v,
    const float* __restrict__ Wp, const float* __restrict__ bp,
    float* __restrict__ qws, ushort_t* __restrict__ khws, ushort_t* __restrict__ vtws)
{
    __shared__ __align__(16) ushort_t Hh[64 * 72];
    __shared__ __align__(16) ushort_t Hl[64 * 72];
    __shared__ __align__(16) ushort_t Vt[64 * 72];
    __shared__ __align__(16) ushort_t PadK1[6656];    // total 40960 B

    const int tid = threadIdx.x;
    const int wv  = tid >> 6;
    const int lane = tid & 63;
    const int l15 = lane & 15;
    const int g   = lane >> 4;
    const int bh  = blockIdx.x & 31;     // b*8 + h
    const int sc  = blockIdx.x >> 5;
    const int b   = bh >> 3, hh = bh & 7;
    const int s0  = sc * 64;

    PadK1[tid] = (ushort_t)tid;
    if (blockIdx.x == 0xFFFFFFFFu) {
        qws[tid] = (float)PadK1[255 - tid];
        return;
    }

    // ---- B-frags built from raw Wp ----
    short8 bqh[2], bql[2], bkh[2], bkl[2], bvh[2];
    {
        const int nq = wv * 16 + l15;
        #pragma unroll
        for (int kh = 0; kh < 2; ++kh) {
            const int koff = kh * 32 + g * 8;
            #pragma unroll
            for (int j = 0; j < 8; ++j) {
                const float* wrow = Wp + (size_t)(koff + j) * 192 + nq;
                float wq = wrow[0];
                ushort_t hq = f2bf(wq);
                bqh[kh][j] = (short)hq;
                bql[kh][j] = (short)f2bf(wq - bf2f(hq));
                float wk = wrow[64];
                ushort_t hk = f2bf(wk);
                bkh[kh][j] = (short)hk;
                bkl[kh][j] = (short)f2bf(wk - bf2f(hk));
                bvh[kh][j] = (short)f2bf(wrow[128]);
            }
        }
    }
    const float biasq = bp[wv * 16 + l15];
    const float biask = bp[64 + wv * 16 + l15];
    const float biasv = bp[128 + wv * 16 + l15];

    // ---- LN for row s0 + wv*16 + l15; lane holds dims 32kh+8g+j ----
    {
        const int srow = s0 + wv * 16 + l15;
        const float* xr = x + ((size_t)(b * 2048 + srow) * 8 + hh) * 64;
        float hvv[16];
        #pragma unroll
        for (int kh = 0; kh < 2; ++kh) {
            float4 p0 = *(const float4*)(xr + kh * 32 + g * 8);
            float4 p1 = *(const float4*)(xr + kh * 32 + g * 8 + 4);
            hvv[kh*8+0]=p0.x; hvv[kh*8+1]=p0.y; hvv[kh*8+2]=p0.z; hvv[kh*8+3]=p0.w;
            hvv[kh*8+4]=p1.x; hvv[kh*8+5]=p1.y; hvv[kh*8+6]=p1.z; hvv[kh*8+7]=p1.w;
        }
        float s1 = 0.0f;
        #pragma unroll
        for (int i = 0; i < 16; ++i) s1 += hvv[i];
        s1 += __shfl_xor(s1, 16, 64);
        s1 += __shfl_xor(s1, 32, 64);
        float mean = s1 * (1.0f / 64.0f);
        float s2 = 0.0f;
        #pragma unroll
        for (int i = 0; i < 16; ++i) { float d = hvv[i] - mean; s2 += d * d; }
        s2 += __shfl_xor(s2, 16, 64);
        s2 += __shfl_xor(s2, 32, 64);
        float rstd = rsqrtf(s2 * (1.0f / 64.0f) + EPSV);

        #pragma unroll
        for (int kh = 0; kh < 2; ++kh) {
            ushort_t hi[8]; unsigned lo2[4];
            float hf[8];
            #pragma unroll
            for (int j = 0; j < 8; ++j) {
                int dI = kh * 32 + g * 8 + j;
                hf[j] = (hvv[kh*8+j] - mean) * rstd * g1[dI] + b1v[dI];
                hi[j] = f2bf(hf[j]);
            }
            uint4 HHv;
            HHv.x = (unsigned)hi[0] | ((unsigned)hi[1] << 16);
            HHv.y = (unsigned)hi[2] | ((unsigned)hi[3] << 16);
            HHv.z = (unsigned)hi[4] | ((unsigned)hi[5] << 16);
            HHv.w = (unsigned)hi[6] | ((unsigned)hi[7] << 16);
            #pragma unroll
            for (int j = 0; j < 4; ++j)
                lo2[j] = pkbf(hf[2*j] - bf2f(hi[2*j]), hf[2*j+1] - bf2f(hi[2*j+1]));
            uint4 HLv; HLv.x = lo2[0]; HLv.y = lo2[1]; HLv.z = lo2[2]; HLv.w = lo2[3];
            int off = (wv * 16 + l15) * 72 + kh * 32 + g * 8;
            *(uint4*)(&Hh[off]) = HHv;
            *(uint4*)(&Hl[off]) = HLv;
        }
    }
    __syncthreads();

    // ---- GEMM over 4 m-tiles of 16 rows ----
    #pragma unroll
    for (int mt = 0; mt < 4; ++mt) {
        short8 ah[2], al[2];
        int abase = (mt * 16 + l15) * 72 + g * 8;
        ah[0] = *(const short8*)(&Hh[abase]);
        ah[1] = *(const short8*)(&Hh[abase + 32]);
        al[0] = *(const short8*)(&Hl[abase]);
        al[1] = *(const short8*)(&Hl[abase + 32]);

        f32x4 aq = (f32x4){0.f,0.f,0.f,0.f};
        f32x4 ak = (f32x4){0.f,0.f,0.f,0.f};
        f32x4 av = (f32x4){0.f,0.f,0.f,0.f};
        #pragma unroll
        for (int kh = 0; kh < 2; ++kh) {
            aq = MFMA16(ah[kh], bqh[kh], aq, 0, 0, 0);
            aq = MFMA16(al[kh], bqh[kh], aq, 0, 0, 0);
            aq = MFMA16(ah[kh], bql[kh], aq, 0, 0, 0);
            ak = MFMA16(ah[kh], bkh[kh], ak, 0, 0, 0);
            ak = MFMA16(al[kh], bkh[kh], ak, 0, 0, 0);
            ak = MFMA16(ah[kh], bkl[kh], ak, 0, 0, 0);
            av = MFMA16(ah[kh], bvh[kh], av, 0, 0, 0);
        }

        size_t base = ((size_t)bh * 2048 + s0 + mt * 16 + 4 * g) * 64 + wv * 16 + l15;
        #pragma unroll
        for (int r = 0; r < 4; ++r) {
            qws[base + (size_t)r * 64] = aq[r] + biasq;
            khws[base + (size_t)r * 64] = f2bf(ak[r] + biask);
        }
        uint2 vvp;
        vvp.x = pkbf(av[0] + biasv, av[1] + biasv);
        vvp.y = pkbf(av[2] + biasv, av[3] + biasv);
        *(uint2*)(&Vt[(wv * 16 + l15) * 72 + mt * 16 + 4 * g]) = vvp;
    }
    __syncthreads();

    // ---- cooperative V^T store with pi-permuted key order ----
    #pragma unroll
    for (int p = 0; p < 2; ++p) {
        int slot = tid + 256 * p;
        int dd = slot >> 3, cc = slot & 7;
        int c0 = ((cc >> 2) << 5) + ((cc & 3) << 2);
        uint2 a = *(const uint2*)(&Vt[dd * 72 + c0]);
        uint2 b2 = *(const uint2*)(&Vt[dd * 72 + c0 + 16]);
        uint4 o; o.x = a.x; o.y = a.y; o.z = b2.x; o.w = b2.y;
        *(uint4*)(vtws + ((size_t)bh * 64 + dd) * 2048 + s0 + cc * 8) = o;
    }
}

// ---------------------------------------------------------------------------
// K2: flash attention, bf16 MFMA. NO-MAX softmax; P in registers via
// pi-permuted V; global_load_lds DMA staging with both-sides XOR swizzle
// (conflicts = 0). EXACT R15 config (best measured 59.3-59.8 us): pad
// 55296 (2-block regime), launch_bounds(256,2). R16's waves_per_eu(3,3)
// did NOT raise occupancy (still 2 blocks, VGPR 84, k2 64) -- reverted;
// occupancy search space for k2 is exhausted (R1/R4/R5/R6/R9/R14/R16).
// R17: epilogue stores ows as BF16 (halves k2-write + k3-read traffic;
// values are bf16-MFMA products re-quantized to bf16 in k3 anyway).
// ---------------------------------------------------------------------------
#define NKT 32

__global__ __launch_bounds__(256, 2) void k2_attn(
    const float* __restrict__ qws, const ushort_t* __restrict__ khws,
    const ushort_t* __restrict__ vtws, ushort_t* __restrict__ owsb)
{
    __shared__ __align__(16) ushort_t KhL[2][64 * 64];
    __shared__ __align__(16) ushort_t VtL[2][64 * 64];   // [dim][pos] pi order
    __shared__ __align__(16) ushort_t PadL[11264];       // total 55296 B

    const int tid  = threadIdx.x;
    const int w    = tid >> 6;
    const int lane = tid & 63;
    const int l15  = lane & 15;
    const int g    = lane >> 4;
    const int bh   = blockIdx.x & 31;
    const int qb0  = (blockIdx.x >> 5) * 128;

    PadL[tid] = (ushort_t)tid;
    if (blockIdx.x == 0xFFFFFFFFu) {
        owsb[tid] = PadL[255 - tid];
        return;
    }

    // ---- Q B-frags x2 subs, scaled by log2(e), split hi/lo ----
    const float LOG2E = 1.4426950408889634f;
    short8 qh[2][2], ql[2][2];
    #pragma unroll
    for (int sub = 0; sub < 2; ++sub) {
        const float* qp = qws + ((size_t)bh * SS + qb0 + w * 32 + sub * 16 + l15) * 64;
        #pragma unroll
        for (int kh = 0; kh < 2; ++kh) {
            const float* p = qp + 32 * kh + 8 * g;
            #pragma unroll
            for (int j = 0; j < 8; ++j) {
                float f = p[j] * LOG2E;
                ushort_t hi = f2bf(f);
                qh[sub][kh][j] = (short)hi;
                ql[sub][kh][j] = (short)f2bf(f - bf2f(hi));
            }
        }
    }

    float lrow[2] = {0.0f, 0.0f};
    f32x4 oacc[2][4];
    #pragma unroll
    for (int sub = 0; sub < 2; ++sub)
        #pragma unroll
        for (int dt = 0; dt < 4; ++dt) oacc[sub][dt] = (f32x4){0.f, 0.f, 0.f, 0.f};

    const size_t kbase = (size_t)bh * SS * 64;
    const size_t vbase = (size_t)bh * 64 * 2048;

    // ---- DMA staging geometry (see R10) ----
    const int dlo  = lane >> 3;                 // row&7 for this lane
    const int j8   = ((lane & 7) ^ dlo) << 3;   // logical slot * 8 ushorts
    const int row0 = w * 8 + dlo;               // rr = 0 rows 0..31
    const int row1 = 32 + row0;                 // rr = 1 rows 32..63
    const int lb0  = (64 * w) * 8;              // LDS ushort offset, rr=0
    const int lb1  = (256 + 64 * w) * 8;        // rr=1

    #define K2_STAGE(buf, tg)                                                   \
        do {                                                                     \
            __builtin_amdgcn_global_load_lds(                                    \
                (const __attribute__((address_space(1))) void*)                  \
                    (khws + kbase + (size_t)((tg) * 64 + row0) * 64 + j8),       \
                (__attribute__((address_space(3))) void*)(&KhL[(buf)][lb0]),     \
                16, 0, 0);                                                       \
            __builtin_amdgcn_global_load_lds(                                    \
                (const __attribute__((address_space(1))) void*)                  \
                    (khws + kbase + (size_t)((tg) * 64 + row1) * 64 + j8),       \
                (__attribute__((address_space(3))) void*)(&KhL[(buf)][lb1]),     \
                16, 0, 0);                                                       \
            __builtin_amdgcn_global_load_lds(                                    \
                (const __attribute__((address_space(1))) void*)                  \
                    (vtws + vbase + (size_t)row0 * 2048 + (tg) * 64 + j8),       \
                (__attribute__((address_space(3))) void*)(&VtL[(buf)][lb0]),     \
                16, 0, 0);                                                       \
            __builtin_amdgcn_global_load_lds(                                    \
                (const __attribute__((address_space(1))) void*)                  \
                    (vtws + vbase + (size_t)row1 * 2048 + (tg) * 64 + j8),       \
                (__attribute__((address_space(3))) void*)(&VtL[(buf)][lb1]),     \
                16, 0, 0);                                                       \
        } while (0)

    K2_STAGE(0, 0);   // prologue: tile 0 -> buffer 0

    const int rsw = l15 & 7;   // read-side XOR key (= row&7 for all reads)

    for (int kt = 0; kt < NKT; ++kt) {
        __syncthreads();       // drains DMA: buffer kt&1 visible; buf^1 free
        const int cur = kt & 1;

        if (kt < NKT - 1) K2_STAGE(cur ^ 1, kt + 1);

        #pragma unroll
        for (int half = 0; half < 2; ++half) {
            uint2 pA[2], pB[2];
            #pragma unroll
            for (int nf2 = 0; nf2 < 2; ++nf2) {
                const int nf = half * 2 + nf2;
                f32x4 aA = (f32x4){0.f, 0.f, 0.f, 0.f};
                f32x4 aB = (f32x4){0.f, 0.f, 0.f, 0.f};
                #pragma unroll
                for (int kh = 0; kh < 2; ++kh) {
                    short8 kah = *(const short8*)(
                        &KhL[cur][(nf * 16 + l15) * 64 + (((4 * kh + g) ^ rsw) << 3)]);
                    aA = MFMA16(kah, qh[0][kh], aA, 0, 0, 0);
                    aA = MFMA16(kah, ql[0][kh], aA, 0, 0, 0);
                    aB = MFMA16(kah, qh[1][kh], aB, 0, 0, 0);
                    aB = MFMA16(kah, ql[1][kh], aB, 0, 0, 0);
                }
                {
                    float p0 = __builtin_amdgcn_exp2f(aA[0]);
                    float p1 = __builtin_amdgcn_exp2f(aA[1]);
                    float p2 = __builtin_amdgcn_exp2f(aA[2]);
                    float p3 = __builtin_amdgcn_exp2f(aA[3]);
                    lrow[0] += (p0 + p1) + (p2 + p3);
                    pA[nf2].x = pkbf(p0, p1); pA[nf2].y = pkbf(p2, p3);
                }
                {
                    float p0 = __builtin_amdgcn_exp2f(aB[0]);
                    float p1 = __builtin_amdgcn_exp2f(aB[1]);
                    float p2 = __builtin_amdgcn_exp2f(aB[2]);
                    float p3 = __builtin_amdgcn_exp2f(aB[3]);
                    lrow[1] += (p0 + p1) + (p2 + p3);
                    pB[nf2].x = pkbf(p0, p1); pB[nf2].y = pkbf(p2, p3);
                }
            }
            short8 paA = __builtin_bit_cast(short8, (uint4v){pA[0].x, pA[0].y, pA[1].x, pA[1].y});
            short8 paB = __builtin_bit_cast(short8, (uint4v){pB[0].x, pB[0].y, pB[1].x, pB[1].y});
            #pragma unroll
            for (int dt = 0; dt < 4; ++dt) {
                short8 vbf = *(const short8*)(
                    &VtL[cur][(16 * dt + l15) * 64 + (((4 * half + g) ^ rsw) << 3)]);
                oacc[0][dt] = MFMA16(paA, vbf, oacc[0][dt], 0, 0, 0);
                oacc[1][dt] = MFMA16(paB, vbf, oacc[1][dt], 0, 0, 0);
            }
        }
    }

    // ---- epilogue: reduce l across lanes once, normalize, store bf16 ----
    #pragma unroll
    for (int sub = 0; sub < 2; ++sub) {
        float l = lrow[sub];
        l += __shfl_xor(l, 16, 64);
        l += __shfl_xor(l, 32, 64);
        float il = 1.0f / l;
        #pragma unroll
        for (int r = 0; r < 4; ++r) {
            float ilr = __shfl(il, 4 * g + r, 64);
            int row = qb0 + w * 32 + sub * 16 + 4 * g + r;
            #pragma unroll
            for (int dt = 0; dt < 4; ++dt)
                owsb[((size_t)bh * SS + row) * 64 + dt * 16 + l15] =
                    f2bf(oacc[sub][dt][r] * ilr);
        }
    }
    #undef K2_STAGE
}

// ---------------------------------------------------------------------------
// K3: LN2 + MLP via bf16 MFMA + residual. Grid 1024, 64 rows/block.
// LN de-duplicated; gelu via A&S erf; bare LDS 36096 B -> 4 blocks/CU.
// R17: Phase-A reads ows as BF16 (short8 loads, half the bytes).
// ---------------------------------------------------------------------------
__global__ __launch_bounds__(256, 2) void k3_ln_mlp(
    const ushort_t* __restrict__ owsb, const float* __restrict__ x,
    const float* __restrict__ g2, const float* __restrict__ b2v,
    const float* __restrict__ W1, const float* __restrict__ b1m,
    const float* __restrict__ W2, const float* __restrict__ b2o,
    float* __restrict__ out)
{
    __shared__ __align__(16) ushort_t Hb[64 * 72];     // LN'd hidden (bf16)
    __shared__ __align__(16) ushort_t Hs[16 * 264];
    __shared__ __align__(16) float Rs[4 * 16 * 72];

    const int tid  = threadIdx.x;
    const int wv   = tid >> 6;
    const int lane = tid & 63;
    const int l15  = lane & 15;
    const int g    = lane >> 4;

    short8 w1f[4][2], w2f[4][2];
    float  b1r[4][4];
    #pragma unroll
    for (int t = 0; t < 4; ++t) {
        #pragma unroll
        for (int kh = 0; kh < 2; ++kh) {
            #pragma unroll
            for (int j = 0; j < 8; ++j) {
                w1f[t][kh][j] = (short)f2bf(
                    W1[(size_t)(kh * 32 + g * 8 + j) * 256 + wv * 64 + t * 16 + l15]);
                w2f[t][kh][j] = (short)f2bf(
                    W2[(size_t)(wv * 64 + kh * 32 + g * 8 + j) * 64 + t * 16 + l15]);
            }
        }
        #pragma unroll
        for (int r = 0; r < 4; ++r)
            b1r[t][r] = b1m[wv * 64 + t * 16 + 4 * g + r];
    }

    const int r0 = blockIdx.x * 64;

    // ---- Phase A: LN of row r0 + wv*16 + l15 (64 distinct rows) -> Hb ----
    {
        const ushort_t* orow = owsb + (size_t)(r0 + wv * 16 + l15) * 64;
        float hvv[16];
        #pragma unroll
        for (int kh = 0; kh < 2; ++kh) {
            short8 pv = *(const short8*)(orow + kh * 32 + g * 8);
            #pragma unroll
            for (int j = 0; j < 8; ++j)
                hvv[kh * 8 + j] = bf2f((ushort_t)pv[j]);
        }
        float s1 = 0.0f;
        #pragma unroll
        for (int i = 0; i < 16; ++i) s1 += hvv[i];
        s1 += __shfl_xor(s1, 16, 64);
        s1 += __shfl_xor(s1, 32, 64);
        float mean = s1 * (1.0f / 64.0f);
        float s2 = 0.0f;
        #pragma unroll
        for (int i = 0; i < 16; ++i) { float d = hvv[i] - mean; s2 += d * d; }
        s2 += __shfl_xor(s2, 16, 64);
        s2 += __shfl_xor(s2, 32, 64);
        float rstd = rsqrtf(s2 * (1.0f / 64.0f) + EPSV);

        #pragma unroll
        for (int kh = 0; kh < 2; ++kh) {
            ushort_t hi[8];
            #pragma unroll
            for (int j = 0; j < 8; ++j) {
                int dI = kh * 32 + g * 8 + j;
                hi[j] = f2bf((hvv[kh*8+j] - mean) * rstd * g2[dI] + b2v[dI]);
            }
            uint4 HHv;
            HHv.x = (unsigned)hi[0] | ((unsigned)hi[1] << 16);
            HHv.y = (unsigned)hi[2] | ((unsigned)hi[3] << 16);
            HHv.z = (unsigned)hi[4] | ((unsigned)hi[5] << 16);
            HHv.w = (unsigned)hi[6] | ((unsigned)hi[7] << 16);
            *(uint4*)(&Hb[(wv * 16 + l15) * 72 + kh * 32 + g * 8]) = HHv;
        }
    }
    __syncthreads();

    // ---- Phase B: per 16-row tile: W1 GEMM + gelu + W2 GEMM + residual ----
    for (int mt = 0; mt < 4; ++mt) {
        short8 h2f[2];
        h2f[0] = *(const short8*)(&Hb[(mt * 16 + l15) * 72 + g * 8]);
        h2f[1] = *(const short8*)(&Hb[(mt * 16 + l15) * 72 + 32 + g * 8]);

        #pragma unroll
        for (int t = 0; t < 4; ++t) {
            f32x4 acc = (f32x4){0.f, 0.f, 0.f, 0.f};
            acc = MFMA16(w1f[t][0], h2f[0], acc, 0, 0, 0);
            acc = MFMA16(w1f[t][1], h2f[1], acc, 0, 0, 0);
            float ge[4];
            #pragma unroll
            for (int r = 0; r < 4; ++r)
                ge[r] = gelu_f(acc[r] + b1r[t][r]);
            uint2 pk;
            pk.x = pkbf(ge[0], ge[1]);
            pk.y = pkbf(ge[2], ge[3]);
            *(uint2*)(&Hs[l15 * 264 + wv * 64 + t * 16 + 4 * g]) = pk;
        }

        short8 ha[2];
        ha[0] = *(const short8*)(&Hs[l15 * 264 + wv * 64 + g * 8]);
        ha[1] = *(const short8*)(&Hs[l15 * 264 + wv * 64 + 32 + g * 8]);
        #pragma unroll
        for (int t = 0; t < 4; ++t) {
            f32x4 a2 = (f32x4){0.f, 0.f, 0.f, 0.f};
            a2 = MFMA16(ha[0], w2f[t][0], a2, 0, 0, 0);
            a2 = MFMA16(ha[1], w2f[t][1], a2, 0, 0, 0);
            #pragma unroll
            for (int r = 0; r < 4; ++r)
                Rs[wv * 1152 + (4 * g + r) * 72 + t * 16 + l15] = a2[r];
        }
        __syncthreads();

        {
            int m = tid >> 4, d4 = tid & 15;
            const float* rp = Rs + m * 72 + d4 * 4;
            f32x4 v0 = *(const f32x4*)(rp);
            f32x4 v1 = *(const f32x4*)(rp + 1152);
            f32x4 v2 = *(const f32x4*)(rp + 2304);
            f32x4 v3 = *(const f32x4*)(rp + 3456);
            f32x4 sum = v0 + v1 + v2 + v3;
            int r = r0 + mt * 16 + m;
            int bq = r >> 14, hq = (r >> 11) & 7, sq = r & 2047;
            size_t oidx = ((size_t)(bq * 2048 + sq) * 8 + hq) * 64 + d4 * 4;
            float4 xv = *(const float4*)(x + oidx);
            float4 bo = *(const float4*)(b2o + d4 * 4);
            float4 res = make_float4(sum[0] + xv.x + bo.x, sum[1] + xv.y + bo.y,
                                     sum[2] + xv.z + bo.z, sum[3] + xv.w + bo.w);
            *(float4*)(out + oidx) = res;
        }
        __syncthreads();
    }
}

// ---------------------------------------------------------------------------
extern "C" void kernel_launch(void* const* d_in, const int* in_sizes, int n_in,
                              void* d_out, int out_size, void* d_ws, size_t ws_size,
                              hipStream_t stream) {
    const float* x     = (const float*)d_in[0];
    const float* ln1_g = (const float*)d_in[1];
    const float* ln1_b = (const float*)d_in[2];
    const float* Wp    = (const float*)d_in[3];
    const float* bp    = (const float*)d_in[4];
    const float* ln2_g = (const float*)d_in[5];
    const float* ln2_b = (const float*)d_in[6];
    const float* W1    = (const float*)d_in[7];
    const float* b1    = (const float*)d_in[8];
    const float* W2    = (const float*)d_in[9];
    const float* b2    = (const float*)d_in[10];
    float* out = (float*)d_out;

    // workspace: qws f32 | khws bf16 | vtws bf16 | owsb bf16
    float* ws  = (float*)d_ws;
    float* qws = ws;
    ushort_t* khws = (ushort_t*)(ws + 4194304);
    ushort_t* vtws = khws + 4194304;
    ushort_t* owsb = vtws + 4194304;

    k1_ln_qkv<<<dim3(1024), dim3(256), 0, stream>>>(
        x, ln1_g, ln1_b, Wp, bp, qws, khws, vtws);
    k2_attn<<<dim3(512), dim3(256), 0, stream>>>(qws, khws, vtws, owsb);
    k3_ln_mlp<<<dim3(1024), dim3(256), 0, stream>>>(
        owsb, x, ln2_g, ln2_b, W1, b1, W2, b2, out);
}

// Round 18
// 163.975 us; speedup vs baseline: 1.0226x; 1.0226x over previous
//
#include <hip/hip_runtime.h>
#include <hip/hip_bf16.h>
#include <math.h>

#define BB 4
#define SS 2048
#define HH 8
#define DD 64
#define EPSV 1e-5f

typedef __attribute__((ext_vector_type(8))) short short8;
typedef __attribute__((ext_vector_type(4))) float f32x4;
typedef __attribute__((ext_vector_type(4))) unsigned int uint4v;
typedef unsigned short ushort_t;
#define MFMA16 __builtin_amdgcn_mfma_f32_16x16x32_bf16

__device__ inline unsigned short f2bf(float f) {
    unsigned u = __builtin_bit_cast(unsigned, f);
    unsigned r = (u + 0x7fffu + ((u >> 16) & 1u)) >> 16;
    return (unsigned short)r;
}
__device__ inline float bf2f(unsigned short h) {
    unsigned u = ((unsigned)h) << 16;
    return __builtin_bit_cast(float, u);
}
__device__ inline unsigned pkbf(float a, float b) {
    __hip_bfloat162 h2 = __float22bfloat162_rn(make_float2(a, b));
    unsigned u;
    __builtin_memcpy(&u, &h2, 4);
    return u;
}
// gelu exact via A&S 7.1.26 erf (|err| <= 1.5e-7): rcp + 5 FMA + exp2.
__device__ inline float gelu_f(float v) {
    float a = v * 0.70710678118654752f;
    float z = fabsf(a);
    float t = __builtin_amdgcn_rcpf(fmaf(0.3275911f, z, 1.0f));
    float p = t * fmaf(t, fmaf(t, fmaf(t, fmaf(t, 1.061405429f, -1.453152027f),
                                       1.421413741f), -0.284496736f), 0.254829592f);
    float e = __builtin_amdgcn_exp2f(-z * z * 1.4426950408889634f);
    float erfz = fmaf(-p, e, 1.0f);
    float se = (a < 0.0f) ? -erfz : erfz;
    return 0.5f * v * (1.0f + se);
}

// ---------------------------------------------------------------------------
// K1: LN1 + QKV projection via bf16 MFMA, split-precision for Q and K.
// B-frags built directly from raw Wp.
// R18: WEIGHT-CONVERSION AMORTIZED 2x -- grid 512 (bh = bx&31, sc-pair =
// bx>>5), each block loops over TWO 64-row s-tiles with the weight frags
// (48 scalar loads + ~100 VALU/thread) built ONCE. Tests the hypothesis
// that k1's cost is the per-block conversion tax (1024x redundant), at the
// price of 2 instead of 4 resident blocks/CU. Q is stored PRE-SCALED by
// log2(e) (k2's per-element scale folded into the k1 epilogue).
// Pad 40960 B (4-block budget 128 >= demand ~125).
// Outputs: Q fp32 (xlog2e); K bf16; V^T bf16 [bh][d][pos], pos = pi-
// permuted key order (pos 8g+j <-> key (j<4 ? 4g+j : 16+4g+j-4)).
// ---------------------------------------------------------------------------
__global__ __launch_bounds__(256, 2) void k1_ln_qkv(
    const float* __restrict__ x, const float* __restrict__ g1, const float* __restrict__ b1v,
    const float* __restrict__ Wp, const float* __restrict__ bp,
    float* __restrict__ qws, ushort_t* __restrict__ khws, ushort_t* __restrict__ vtws)
{
    __shared__ __align__(16) ushort_t Hh[64 * 72];
    __shared__ __align__(16) ushort_t Hl[64 * 72];
    __shared__ __align__(16) ushort_t Vt[64 * 72];
    __shared__ __align__(16) ushort_t PadK1[6656];    // total 40960 B

    const int tid = threadIdx.x;
    const int wv  = tid >> 6;
    const int lane = tid & 63;
    const int l15 = lane & 15;
    const int g   = lane >> 4;
    const int bh  = blockIdx.x & 31;     // b*8 + h
    const int scp = blockIdx.x >> 5;     // s-tile pair index (0..15)
    const int b   = bh >> 3, hh = bh & 7;

    PadK1[tid] = (ushort_t)tid;
    if (blockIdx.x == 0xFFFFFFFFu) {
        qws[tid] = (float)PadK1[255 - tid];
        return;
    }

    // ---- B-frags built from raw Wp (ONCE per block, amortized 2x) ----
    short8 bqh[2], bql[2], bkh[2], bkl[2], bvh[2];
    {
        const int nq = wv * 16 + l15;
        #pragma unroll
        for (int kh = 0; kh < 2; ++kh) {
            const int koff = kh * 32 + g * 8;
            #pragma unroll
            for (int j = 0; j < 8; ++j) {
                const float* wrow = Wp + (size_t)(koff + j) * 192 + nq;
                float wq = wrow[0];
                ushort_t hq = f2bf(wq);
                bqh[kh][j] = (short)hq;
                bql[kh][j] = (short)f2bf(wq - bf2f(hq));
                float wk = wrow[64];
                ushort_t hk = f2bf(wk);
                bkh[kh][j] = (short)hk;
                bkl[kh][j] = (short)f2bf(wk - bf2f(hk));
                bvh[kh][j] = (short)f2bf(wrow[128]);
            }
        }
    }
    const float biasq = bp[wv * 16 + l15];
    const float biask = bp[64 + wv * 16 + l15];
    const float biasv = bp[128 + wv * 16 + l15];
    const float LOG2E = 1.4426950408889634f;

    for (int it = 0; it < 2; ++it) {
        const int s0 = (scp * 2 + it) * 64;

        // ---- LN for row s0 + wv*16 + l15; lane holds dims 32kh+8g+j ----
        {
            const int srow = s0 + wv * 16 + l15;
            const float* xr = x + ((size_t)(b * 2048 + srow) * 8 + hh) * 64;
            float hvv[16];
            #pragma unroll
            for (int kh = 0; kh < 2; ++kh) {
                float4 p0 = *(const float4*)(xr + kh * 32 + g * 8);
                float4 p1 = *(const float4*)(xr + kh * 32 + g * 8 + 4);
                hvv[kh*8+0]=p0.x; hvv[kh*8+1]=p0.y; hvv[kh*8+2]=p0.z; hvv[kh*8+3]=p0.w;
                hvv[kh*8+4]=p1.x; hvv[kh*8+5]=p1.y; hvv[kh*8+6]=p1.z; hvv[kh*8+7]=p1.w;
            }
            float s1 = 0.0f;
            #pragma unroll
            for (int i = 0; i < 16; ++i) s1 += hvv[i];
            s1 += __shfl_xor(s1, 16, 64);
            s1 += __shfl_xor(s1, 32, 64);
            float mean = s1 * (1.0f / 64.0f);
            float s2 = 0.0f;
            #pragma unroll
            for (int i = 0; i < 16; ++i) { float d = hvv[i] - mean; s2 += d * d; }
            s2 += __shfl_xor(s2, 16, 64);
            s2 += __shfl_xor(s2, 32, 64);
            float rstd = rsqrtf(s2 * (1.0f / 64.0f) + EPSV);

            #pragma unroll
            for (int kh = 0; kh < 2; ++kh) {
                ushort_t hi[8]; unsigned lo2[4];
                float hf[8];
                #pragma unroll
                for (int j = 0; j < 8; ++j) {
                    int dI = kh * 32 + g * 8 + j;
                    hf[j] = (hvv[kh*8+j] - mean) * rstd * g1[dI] + b1v[dI];
                    hi[j] = f2bf(hf[j]);
                }
                uint4 HHv;
                HHv.x = (unsigned)hi[0] | ((unsigned)hi[1] << 16);
                HHv.y = (unsigned)hi[2] | ((unsigned)hi[3] << 16);
                HHv.z = (unsigned)hi[4] | ((unsigned)hi[5] << 16);
                HHv.w = (unsigned)hi[6] | ((unsigned)hi[7] << 16);
                #pragma unroll
                for (int j = 0; j < 4; ++j)
                    lo2[j] = pkbf(hf[2*j] - bf2f(hi[2*j]), hf[2*j+1] - bf2f(hi[2*j+1]));
                uint4 HLv; HLv.x = lo2[0]; HLv.y = lo2[1]; HLv.z = lo2[2]; HLv.w = lo2[3];
                int off = (wv * 16 + l15) * 72 + kh * 32 + g * 8;
                *(uint4*)(&Hh[off]) = HHv;
                *(uint4*)(&Hl[off]) = HLv;
            }
        }
        __syncthreads();

        // ---- GEMM over 4 m-tiles of 16 rows ----
        #pragma unroll
        for (int mt = 0; mt < 4; ++mt) {
            short8 ah[2], al[2];
            int abase = (mt * 16 + l15) * 72 + g * 8;
            ah[0] = *(const short8*)(&Hh[abase]);
            ah[1] = *(const short8*)(&Hh[abase + 32]);
            al[0] = *(const short8*)(&Hl[abase]);
            al[1] = *(const short8*)(&Hl[abase + 32]);

            f32x4 aq = (f32x4){0.f,0.f,0.f,0.f};
            f32x4 ak = (f32x4){0.f,0.f,0.f,0.f};
            f32x4 av = (f32x4){0.f,0.f,0.f,0.f};
            #pragma unroll
            for (int kh = 0; kh < 2; ++kh) {
                aq = MFMA16(ah[kh], bqh[kh], aq, 0, 0, 0);
                aq = MFMA16(al[kh], bqh[kh], aq, 0, 0, 0);
                aq = MFMA16(ah[kh], bql[kh], aq, 0, 0, 0);
                ak = MFMA16(ah[kh], bkh[kh], ak, 0, 0, 0);
                ak = MFMA16(al[kh], bkh[kh], ak, 0, 0, 0);
                ak = MFMA16(ah[kh], bkl[kh], ak, 0, 0, 0);
                av = MFMA16(ah[kh], bvh[kh], av, 0, 0, 0);
            }

            size_t base = ((size_t)bh * 2048 + s0 + mt * 16 + 4 * g) * 64 + wv * 16 + l15;
            #pragma unroll
            for (int r = 0; r < 4; ++r) {
                qws[base + (size_t)r * 64] = (aq[r] + biasq) * LOG2E;
                khws[base + (size_t)r * 64] = f2bf(ak[r] + biask);
            }
            uint2 vvp;
            vvp.x = pkbf(av[0] + biasv, av[1] + biasv);
            vvp.y = pkbf(av[2] + biasv, av[3] + biasv);
            *(uint2*)(&Vt[(wv * 16 + l15) * 72 + mt * 16 + 4 * g]) = vvp;
        }
        __syncthreads();

        // ---- cooperative V^T store with pi-permuted key order ----
        #pragma unroll
        for (int p = 0; p < 2; ++p) {
            int slot = tid + 256 * p;
            int dd = slot >> 3, cc = slot & 7;
            int c0 = ((cc >> 2) << 5) + ((cc & 3) << 2);
            uint2 a = *(const uint2*)(&Vt[dd * 72 + c0]);
            uint2 b2 = *(const uint2*)(&Vt[dd * 72 + c0 + 16]);
            uint4 o; o.x = a.x; o.y = a.y; o.z = b2.x; o.w = b2.y;
            *(uint4*)(vtws + ((size_t)bh * 64 + dd) * 2048 + s0 + cc * 8) = o;
        }
        __syncthreads();    // protect Hh/Hl/Vt for the next iteration
    }
}

// ---------------------------------------------------------------------------
// K2: flash attention, bf16 MFMA. NO-MAX softmax; P in registers via
// pi-permuted V; global_load_lds DMA staging with both-sides XOR swizzle
// (conflicts = 0). EXACT R17 kernel except Q arrives PRE-SCALED by log2(e)
// (k1 folds the scale), removing 32 v_mul from the prologue.
// Pad 55296 (2-block regime), launch_bounds(256,2) -- the only clean
// allocator config (R1/R4/R5/R6/R9/R14/R16 all failed). bf16 ows output.
// ---------------------------------------------------------------------------
#define NKT 32

__global__ __launch_bounds__(256, 2) void k2_attn(
    const float* __restrict__ qws, const ushort_t* __restrict__ khws,
    const ushort_t* __restrict__ vtws, ushort_t* __restrict__ owsb)
{
    __shared__ __align__(16) ushort_t KhL[2][64 * 64];
    __shared__ __align__(16) ushort_t VtL[2][64 * 64];   // [dim][pos] pi order
    __shared__ __align__(16) ushort_t PadL[11264];       // total 55296 B

    const int tid  = threadIdx.x;
    const int w    = tid >> 6;
    const int lane = tid & 63;
    const int l15  = lane & 15;
    const int g    = lane >> 4;
    const int bh   = blockIdx.x & 31;
    const int qb0  = (blockIdx.x >> 5) * 128;

    PadL[tid] = (ushort_t)tid;
    if (blockIdx.x == 0xFFFFFFFFu) {
        owsb[tid] = PadL[255 - tid];
        return;
    }

    // ---- Q B-frags x2 subs (pre-scaled by log2e in k1), split hi/lo ----
    short8 qh[2][2], ql[2][2];
    #pragma unroll
    for (int sub = 0; sub < 2; ++sub) {
        const float* qp = qws + ((size_t)bh * SS + qb0 + w * 32 + sub * 16 + l15) * 64;
        #pragma unroll
        for (int kh = 0; kh < 2; ++kh) {
            const float* p = qp + 32 * kh + 8 * g;
            #pragma unroll
            for (int j = 0; j < 8; ++j) {
                float f = p[j];
                ushort_t hi = f2bf(f);
                qh[sub][kh][j] = (short)hi;
                ql[sub][kh][j] = (short)f2bf(f - bf2f(hi));
            }
        }
    }

    float lrow[2] = {0.0f, 0.0f};
    f32x4 oacc[2][4];
    #pragma unroll
    for (int sub = 0; sub < 2; ++sub)
        #pragma unroll
        for (int dt = 0; dt < 4; ++dt) oacc[sub][dt] = (f32x4){0.f, 0.f, 0.f, 0.f};

    const size_t kbase = (size_t)bh * SS * 64;
    const size_t vbase = (size_t)bh * 64 * 2048;

    // ---- DMA staging geometry (see R10) ----
    const int dlo  = lane >> 3;                 // row&7 for this lane
    const int j8   = ((lane & 7) ^ dlo) << 3;   // logical slot * 8 ushorts
    const int row0 = w * 8 + dlo;               // rr = 0 rows 0..31
    const int row1 = 32 + row0;                 // rr = 1 rows 32..63
    const int lb0  = (64 * w) * 8;              // LDS ushort offset, rr=0
    const int lb1  = (256 + 64 * w) * 8;        // rr=1

    #define K2_STAGE(buf, tg)                                                   \
        do {                                                                     \
            __builtin_amdgcn_global_load_lds(                                    \
                (const __attribute__((address_space(1))) void*)                  \
                    (khws + kbase + (size_t)((tg) * 64 + row0) * 64 + j8),       \
                (__attribute__((address_space(3))) void*)(&KhL[(buf)][lb0]),     \
                16, 0, 0);                                                       \
            __builtin_amdgcn_global_load_lds(                                    \
                (const __attribute__((address_space(1))) void*)                  \
                    (khws + kbase + (size_t)((tg) * 64 + row1) * 64 + j8),       \
                (__attribute__((address_space(3))) void*)(&KhL[(buf)][lb1]),     \
                16, 0, 0);                                                       \
            __builtin_amdgcn_global_load_lds(                                    \
                (const __attribute__((address_space(1))) void*)                  \
                    (vtws + vbase + (size_t)row0 * 2048 + (tg) * 64 + j8),       \
                (__attribute__((address_space(3))) void*)(&VtL[(buf)][lb0]),     \
                16, 0, 0);                                                       \
            __builtin_amdgcn_global_load_lds(                                    \
                (const __attribute__((address_space(1))) void*)                  \
                    (vtws + vbase + (size_t)row1 * 2048 + (tg) * 64 + j8),       \
                (__attribute__((address_space(3))) void*)(&VtL[(buf)][lb1]),     \
                16, 0, 0);                                                       \
        } while (0)

    K2_STAGE(0, 0);   // prologue: tile 0 -> buffer 0

    const int rsw = l15 & 7;   // read-side XOR key (= row&7 for all reads)

    for (int kt = 0; kt < NKT; ++kt) {
        __syncthreads();       // drains DMA: buffer kt&1 visible; buf^1 free
        const int cur = kt & 1;

        if (kt < NKT - 1) K2_STAGE(cur ^ 1, kt + 1);

        #pragma unroll
        for (int half = 0; half < 2; ++half) {
            uint2 pA[2], pB[2];
            #pragma unroll
            for (int nf2 = 0; nf2 < 2; ++nf2) {
                const int nf = half * 2 + nf2;
                f32x4 aA = (f32x4){0.f, 0.f, 0.f, 0.f};
                f32x4 aB = (f32x4){0.f, 0.f, 0.f, 0.f};
                #pragma unroll
                for (int kh = 0; kh < 2; ++kh) {
                    short8 kah = *(const short8*)(
                        &KhL[cur][(nf * 16 + l15) * 64 + (((4 * kh + g) ^ rsw) << 3)]);
                    aA = MFMA16(kah, qh[0][kh], aA, 0, 0, 0);
                    aA = MFMA16(kah, ql[0][kh], aA, 0, 0, 0);
                    aB = MFMA16(kah, qh[1][kh], aB, 0, 0, 0);
                    aB = MFMA16(kah, ql[1][kh], aB, 0, 0, 0);
                }
                {
                    float p0 = __builtin_amdgcn_exp2f(aA[0]);
                    float p1 = __builtin_amdgcn_exp2f(aA[1]);
                    float p2 = __builtin_amdgcn_exp2f(aA[2]);
                    float p3 = __builtin_amdgcn_exp2f(aA[3]);
                    lrow[0] += (p0 + p1) + (p2 + p3);
                    pA[nf2].x = pkbf(p0, p1); pA[nf2].y = pkbf(p2, p3);
                }
                {
                    float p0 = __builtin_amdgcn_exp2f(aB[0]);
                    float p1 = __builtin_amdgcn_exp2f(aB[1]);
                    float p2 = __builtin_amdgcn_exp2f(aB[2]);
                    float p3 = __builtin_amdgcn_exp2f(aB[3]);
                    lrow[1] += (p0 + p1) + (p2 + p3);
                    pB[nf2].x = pkbf(p0, p1); pB[nf2].y = pkbf(p2, p3);
                }
            }
            short8 paA = __builtin_bit_cast(short8, (uint4v){pA[0].x, pA[0].y, pA[1].x, pA[1].y});
            short8 paB = __builtin_bit_cast(short8, (uint4v){pB[0].x, pB[0].y, pB[1].x, pB[1].y});
            #pragma unroll
            for (int dt = 0; dt < 4; ++dt) {
                short8 vbf = *(const short8*)(
                    &VtL[cur][(16 * dt + l15) * 64 + (((4 * half + g) ^ rsw) << 3)]);
                oacc[0][dt] = MFMA16(paA, vbf, oacc[0][dt], 0, 0, 0);
                oacc[1][dt] = MFMA16(paB, vbf, oacc[1][dt], 0, 0, 0);
            }
        }
    }

    // ---- epilogue: reduce l across lanes once, normalize, store bf16 ----
    #pragma unroll
    for (int sub = 0; sub < 2; ++sub) {
        float l = lrow[sub];
        l += __shfl_xor(l, 16, 64);
        l += __shfl_xor(l, 32, 64);
        float il = 1.0f / l;
        #pragma unroll
        for (int r = 0; r < 4; ++r) {
            float ilr = __shfl(il, 4 * g + r, 64);
            int row = qb0 + w * 32 + sub * 16 + 4 * g + r;
            #pragma unroll
            for (int dt = 0; dt < 4; ++dt)
                owsb[((size_t)bh * SS + row) * 64 + dt * 16 + l15] =
                    f2bf(oacc[sub][dt][r] * ilr);
        }
    }
    #undef K2_STAGE
}

// ---------------------------------------------------------------------------
// K3: LN2 + MLP via bf16 MFMA + residual. Grid 1024, 64 rows/block.
// LN de-duplicated; gelu via A&S erf; bare LDS 36096 B -> 4 blocks/CU;
// Phase-A reads ows as BF16. EXACT R17 kernel.
// ---------------------------------------------------------------------------
__global__ __launch_bounds__(256, 2) void k3_ln_mlp(
    const ushort_t* __restrict__ owsb, const float* __restrict__ x,
    const float* __restrict__ g2, const float* __restrict__ b2v,
    const float* __restrict__ W1, const float* __restrict__ b1m,
    const float* __restrict__ W2, const float* __restrict__ b2o,
    float* __restrict__ out)
{
    __shared__ __align__(16) ushort_t Hb[64 * 72];     // LN'd hidden (bf16)
    __shared__ __align__(16) ushort_t Hs[16 * 264];
    __shared__ __align__(16) float Rs[4 * 16 * 72];

    const int tid  = threadIdx.x;
    const int wv   = tid >> 6;
    const int lane = tid & 63;
    const int l15  = lane & 15;
    const int g    = lane >> 4;

    short8 w1f[4][2], w2f[4][2];
    float  b1r[4][4];
    #pragma unroll
    for (int t = 0; t < 4; ++t) {
        #pragma unroll
        for (int kh = 0; kh < 2; ++kh) {
            #pragma unroll
            for (int j = 0; j < 8; ++j) {
                w1f[t][kh][j] = (short)f2bf(
                    W1[(size_t)(kh * 32 + g * 8 + j) * 256 + wv * 64 + t * 16 + l15]);
                w2f[t][kh][j] = (short)f2bf(
                    W2[(size_t)(wv * 64 + kh * 32 + g * 8 + j) * 64 + t * 16 + l15]);
            }
        }
        #pragma unroll
        for (int r = 0; r < 4; ++r)
            b1r[t][r] = b1m[wv * 64 + t * 16 + 4 * g + r];
    }

    const int r0 = blockIdx.x * 64;

    // ---- Phase A: LN of row r0 + wv*16 + l15 (64 distinct rows) -> Hb ----
    {
        const ushort_t* orow = owsb + (size_t)(r0 + wv * 16 + l15) * 64;
        float hvv[16];
        #pragma unroll
        for (int kh = 0; kh < 2; ++kh) {
            short8 pv = *(const short8*)(orow + kh * 32 + g * 8);
            #pragma unroll
            for (int j = 0; j < 8; ++j)
                hvv[kh * 8 + j] = bf2f((ushort_t)pv[j]);
        }
        float s1 = 0.0f;
        #pragma unroll
        for (int i = 0; i < 16; ++i) s1 += hvv[i];
        s1 += __shfl_xor(s1, 16, 64);
        s1 += __shfl_xor(s1, 32, 64);
        float mean = s1 * (1.0f / 64.0f);
        float s2 = 0.0f;
        #pragma unroll
        for (int i = 0; i < 16; ++i) { float d = hvv[i] - mean; s2 += d * d; }
        s2 += __shfl_xor(s2, 16, 64);
        s2 += __shfl_xor(s2, 32, 64);
        float rstd = rsqrtf(s2 * (1.0f / 64.0f) + EPSV);

        #pragma unroll
        for (int kh = 0; kh < 2; ++kh) {
            ushort_t hi[8];
            #pragma unroll
            for (int j = 0; j < 8; ++j) {
                int dI = kh * 32 + g * 8 + j;
                hi[j] = f2bf((hvv[kh*8+j] - mean) * rstd * g2[dI] + b2v[dI]);
            }
            uint4 HHv;
            HHv.x = (unsigned)hi[0] | ((unsigned)hi[1] << 16);
            HHv.y = (unsigned)hi[2] | ((unsigned)hi[3] << 16);
            HHv.z = (unsigned)hi[4] | ((unsigned)hi[5] << 16);
            HHv.w = (unsigned)hi[6] | ((unsigned)hi[7] << 16);
            *(uint4*)(&Hb[(wv * 16 + l15) * 72 + kh * 32 + g * 8]) = HHv;
        }
    }
    __syncthreads();

    // ---- Phase B: per 16-row tile: W1 GEMM + gelu + W2 GEMM + residual ----
    for (int mt = 0; mt < 4; ++mt) {
        short8 h2f[2];
        h2f[0] = *(const short8*)(&Hb[(mt * 16 + l15) * 72 + g * 8]);
        h2f[1] = *(const short8*)(&Hb[(mt * 16 + l15) * 72 + 32 + g * 8]);

        #pragma unroll
        for (int t = 0; t < 4; ++t) {
            f32x4 acc = (f32x4){0.f, 0.f, 0.f, 0.f};
            acc = MFMA16(w1f[t][0], h2f[0], acc, 0, 0, 0);
            acc = MFMA16(w1f[t][1], h2f[1], acc, 0, 0, 0);
            float ge[4];
            #pragma unroll
            for (int r = 0; r < 4; ++r)
                ge[r] = gelu_f(acc[r] + b1r[t][r]);
            uint2 pk;
            pk.x = pkbf(ge[0], ge[1]);
            pk.y = pkbf(ge[2], ge[3]);
            *(uint2*)(&Hs[l15 * 264 + wv * 64 + t * 16 + 4 * g]) = pk;
        }

        short8 ha[2];
        ha[0] = *(const short8*)(&Hs[l15 * 264 + wv * 64 + g * 8]);
        ha[1] = *(const short8*)(&Hs[l15 * 264 + wv * 64 + 32 + g * 8]);
        #pragma unroll
        for (int t = 0; t < 4; ++t) {
            f32x4 a2 = (f32x4){0.f, 0.f, 0.f, 0.f};
            a2 = MFMA16(ha[0], w2f[t][0], a2, 0, 0, 0);
            a2 = MFMA16(ha[1], w2f[t][1], a2, 0, 0, 0);
            #pragma unroll
            for (int r = 0; r < 4; ++r)
                Rs[wv * 1152 + (4 * g + r) * 72 + t * 16 + l15] = a2[r];
        }
        __syncthreads();

        {
            int m = tid >> 4, d4 = tid & 15;
            const float* rp = Rs + m * 72 + d4 * 4;
            f32x4 v0 = *(const f32x4*)(rp);
            f32x4 v1 = *(const f32x4*)(rp + 1152);
            f32x4 v2 = *(const f32x4*)(rp + 2304);
            f32x4 v3 = *(const f32x4*)(rp + 3456);
            f32x4 sum = v0 + v1 + v2 + v3;
            int r = r0 + mt * 16 + m;
            int bq = r >> 14, hq = (r >> 11) & 7, sq = r & 2047;
            size_t oidx = ((size_t)(bq * 2048 + sq) * 8 + hq) * 64 + d4 * 4;
            float4 xv = *(const float4*)(x + oidx);
            float4 bo = *(const float4*)(b2o + d4 * 4);
            float4 res = make_float4(sum[0] + xv.x + bo.x, sum[1] + xv.y + bo.y,
                                     sum[2] + xv.z + bo.z, sum[3] + xv.w + bo.w);
            *(float4*)(out + oidx) = res;
        }
        __syncthreads();
    }
}

// ---------------------------------------------------------------------------
extern "C" void kernel_launch(void* const* d_in, const int* in_sizes, int n_in,
                              void* d_out, int out_size, void* d_ws, size_t ws_size,
                              hipStream_t stream) {
    const float* x     = (const float*)d_in[0];
    const float* ln1_g = (const float*)d_in[1];
    const float* ln1_b = (const float*)d_in[2];
    const float* Wp    = (const float*)d_in[3];
    const float* bp    = (const float*)d_in[4];
    const float* ln2_g = (const float*)d_in[5];
    const float* ln2_b = (const float*)d_in[6];
    const float* W1    = (const float*)d_in[7];
    const float* b1    = (const float*)d_in[8];
    const float* W2    = (const float*)d_in[9];
    const float* b2    = (const float*)d_in[10];
    float* out = (float*)d_out;

    // workspace: qws f32 | khws bf16 | vtws bf16 | owsb bf16
    float* ws  = (float*)d_ws;
    float* qws = ws;
    ushort_t* khws = (ushort_t*)(ws + 4194304);
    ushort_t* vtws = khws + 4194304;
    ushort_t* owsb = vtws + 4194304;

    k1_ln_qkv<<<dim3(512), dim3(256), 0, stream>>>(
        x, ln1_g, ln1_b, Wp, bp, qws, khws, vtws);
    k2_attn<<<dim3(512), dim3(256), 0, stream>>>(qws, khws, vtws, owsb);
    k3_ln_mlp<<<dim3(1024), dim3(256), 0, stream>>>(
        owsb, x, ln2_g, ln2_b, W1, b1, W2, b2, out);
}